// Round 10
// baseline (161.846 us; speedup 1.0000x reference)
//
#include <hip/hip_runtime.h>
#include <hip/hip_bf16.h>

#define NUM_EXPERTS 16
#define IN_DIM 1024
#define OUT_DIM 1024
#define BTOK 8192
#define NSLOT (2 * BTOK)
#define MAX_DESC 80    // sum_e ceil(ne/256) <= 16384/256 + 16
#define NGATE 512      // gate blocks: 256 threads, 16 tokens (4 per wave)
#define NCONV 512      // convert blocks: 32768 We elems each

typedef __attribute__((ext_vector_type(4))) float f32x4;
typedef __attribute__((ext_vector_type(4))) int   i32x4;
typedef __attribute__((ext_vector_type(4))) unsigned short u16x4;
typedef __attribute__((ext_vector_type(8))) short short8;
typedef __attribute__((ext_vector_type(8))) __bf16 bf16x8;

// ---- helpers -------------------------------------------------------------

static __device__ inline unsigned short f2bf(float f) {
    union { float f; unsigned u; } v; v.f = f;
    unsigned u = v.u;
    unsigned r = (u + 0x7FFFu + ((u >> 16) & 1u)) >> 16;  // RNE
    return (unsigned short)r;
}

static __device__ inline float bf2f(unsigned short b) {
    union { unsigned u; float f; } v; v.u = ((unsigned)b) << 16;
    return v.f;
}

static __device__ inline short8 pack8v(f32x4 a, f32x4 b) {
    short8 s;
    s[0] = (short)f2bf(a[0]); s[1] = (short)f2bf(a[1]);
    s[2] = (short)f2bf(a[2]); s[3] = (short)f2bf(a[3]);
    s[4] = (short)f2bf(b[0]); s[5] = (short)f2bf(b[1]);
    s[6] = (short)f2bf(b[2]); s[7] = (short)f2bf(b[3]);
    return s;
}

static __device__ inline short8 pack8(float4 a, float4 b) {
    short8 s;
    s[0] = (short)f2bf(a.x); s[1] = (short)f2bf(a.y);
    s[2] = (short)f2bf(a.z); s[3] = (short)f2bf(a.w);
    s[4] = (short)f2bf(b.x); s[5] = (short)f2bf(b.y);
    s[6] = (short)f2bf(b.z); s[7] = (short)f2bf(b.w);
    return s;
}

static __device__ inline bf16x8 ldfrag(const unsigned short* p) {
    i32x4 v = *(const i32x4*)p;                 // ds_read_b128
    return __builtin_bit_cast(bf16x8, v);
}

#define GLOAD_LDS16(g, l)                                                     \
    __builtin_amdgcn_global_load_lds(                                         \
        (const __attribute__((address_space(1))) void*)(g),                   \
        (__attribute__((address_space(3))) void*)(l), 16, 0, 0)

// ---- kernel 1: prep = gate+xb (0..511) || We->bf16 nt-stream (512..1023) ---
// Both roles LDS-free & high occupancy (R7 lesson: the 64KB-LDS gate role is
// gone). Convert uses nontemporal ld/st so its 96 MB stream doesn't evict
// L2-hot Wg.
__global__ __launch_bounds__(256) void prep_kernel(
    const float* __restrict__ x, const float* __restrict__ Wg,
    const float* __restrict__ bg,
    int* __restrict__ eidx, float* __restrict__ prob,
    float* __restrict__ partialLoad, int* __restrict__ partialCount,
    unsigned short* __restrict__ xb,
    const float* __restrict__ We, unsigned short* __restrict__ Web)
{
    __shared__ float sLoad[NUM_EXPERTS];
    __shared__ int   sCnt[NUM_EXPERTS];

    int tid = threadIdx.x, lane = tid & 63, wave = tid >> 6;

    if (blockIdx.x >= NGATE) {
        if (Web != nullptr) {
            int cb = blockIdx.x - NGATE;
            #pragma unroll 4
            for (int i = 0; i < 16; ++i) {
                size_t off = (((size_t)cb * 16 + i) * 256 + tid) * 8;
                f32x4 v0 = __builtin_nontemporal_load((const f32x4*)(We + off));
                f32x4 v1 = __builtin_nontemporal_load((const f32x4*)(We + off + 4));
                __builtin_nontemporal_store(pack8v(v0, v1), (short8*)(Web + off));
            }
        }
        return;
    }

    if (tid < NUM_EXPERTS) { sLoad[tid] = 0.f; sCnt[tid] = 0; }
    __syncthreads();

    const bool wb = (xb != nullptr);
    int tbase = blockIdx.x * 16 + wave * 4;

    const float4* xr0 = (const float4*)(x + (size_t)(tbase + 0) * IN_DIM);
    const float4* xr1 = (const float4*)(x + (size_t)(tbase + 1) * IN_DIM);
    const float4* xr2 = (const float4*)(x + (size_t)(tbase + 2) * IN_DIM);
    const float4* xr3 = (const float4*)(x + (size_t)(tbase + 3) * IN_DIM);

    float acc0[NUM_EXPERTS], acc1[NUM_EXPERTS], acc2[NUM_EXPERTS], acc3[NUM_EXPERTS];
    #pragma unroll
    for (int e = 0; e < NUM_EXPERTS; ++e) { acc0[e]=0.f; acc1[e]=0.f; acc2[e]=0.f; acc3[e]=0.f; }

    #pragma unroll
    for (int pass = 0; pass < 4; ++pass) {
        float4 xv0 = xr0[pass * 64 + lane];
        float4 xv1 = xr1[pass * 64 + lane];
        float4 xv2 = xr2[pass * 64 + lane];
        float4 xv3 = xr3[pass * 64 + lane];
        if (wb) {
            u16x4 b0, b1, b2, b3;
            b0[0]=f2bf(xv0.x); b0[1]=f2bf(xv0.y); b0[2]=f2bf(xv0.z); b0[3]=f2bf(xv0.w);
            b1[0]=f2bf(xv1.x); b1[1]=f2bf(xv1.y); b1[2]=f2bf(xv1.z); b1[3]=f2bf(xv1.w);
            b2[0]=f2bf(xv2.x); b2[1]=f2bf(xv2.y); b2[2]=f2bf(xv2.z); b2[3]=f2bf(xv2.w);
            b3[0]=f2bf(xv3.x); b3[1]=f2bf(xv3.y); b3[2]=f2bf(xv3.z); b3[3]=f2bf(xv3.w);
            size_t c = (size_t)(pass * 64 + lane) * 4;
            *(u16x4*)(xb + (size_t)(tbase + 0) * IN_DIM + c) = b0;
            *(u16x4*)(xb + (size_t)(tbase + 1) * IN_DIM + c) = b1;
            *(u16x4*)(xb + (size_t)(tbase + 2) * IN_DIM + c) = b2;
            *(u16x4*)(xb + (size_t)(tbase + 3) * IN_DIM + c) = b3;
        }
        int kb = pass * 256 + lane * 4;
        #pragma unroll
        for (int e = 0; e < NUM_EXPERTS; ++e) {
            float4 wv = *(const float4*)(Wg + e * IN_DIM + kb);
            acc0[e] += xv0.x*wv.x + xv0.y*wv.y + xv0.z*wv.z + xv0.w*wv.w;
            acc1[e] += xv1.x*wv.x + xv1.y*wv.y + xv1.z*wv.z + xv1.w*wv.w;
            acc2[e] += xv2.x*wv.x + xv2.y*wv.y + xv2.z*wv.z + xv2.w*wv.w;
            acc3[e] += xv3.x*wv.x + xv3.y*wv.y + xv3.z*wv.z + xv3.w*wv.w;
        }
    }

    #pragma unroll
    for (int e = 0; e < NUM_EXPERTS; ++e) {
        float v0 = acc0[e], v1 = acc1[e], v2 = acc2[e], v3 = acc3[e];
        #pragma unroll
        for (int off = 32; off; off >>= 1) {
            v0 += __shfl_xor(v0, off);
            v1 += __shfl_xor(v1, off);
            v2 += __shfl_xor(v2, off);
            v3 += __shfl_xor(v3, off);
        }
        acc0[e] = v0; acc1[e] = v1; acc2[e] = v2; acc3[e] = v3;
    }

    if (lane == 0) {
        #pragma unroll
        for (int j = 0; j < 4; ++j) {
            int t = tbase + j;
            float v0 = -1e30f, v1 = -1e30f; int i0 = 0, i1 = 0;
            #pragma unroll
            for (int e = 0; e < NUM_EXPERTS; ++e) {
                float a = (j == 0) ? acc0[e] : (j == 1) ? acc1[e]
                        : (j == 2) ? acc2[e] : acc3[e];
                float v = a + bg[e];
                if (v > v0) { v1 = v0; i1 = i0; v0 = v; i0 = e; }
                else if (v > v1) { v1 = v; i1 = e; }
            }
            float t1 = expf(v1 - v0);           // v1 <= v0
            float inv = 1.f / (1.f + t1);
            float p0 = inv, p1 = t1 * inv;
            eidx[2 * t]     = i0;  eidx[2 * t + 1] = i1;
            prob[2 * t]     = p0;  prob[2 * t + 1] = p1;
            atomicAdd(&sCnt[i0], 1);
            atomicAdd(&sCnt[i1], 1);
            atomicAdd(&sLoad[i0], p0);
            atomicAdd(&sLoad[i1], p1);
        }
    }
    __syncthreads();
    if (tid < NUM_EXPERTS) {
        partialLoad[blockIdx.x * NUM_EXPERTS + tid]  = sLoad[tid];
        partialCount[blockIdx.x * NUM_EXPERTS + tid] = sCnt[tid];
    }
}

// ---- kernel 2: offsets + aux loss + tile-descriptor list (256-row tiles) ---
__global__ __launch_bounds__(256) void finalize_gate(
    int* __restrict__ offsets, int* __restrict__ cursor,
    const float* __restrict__ partialLoad, const int* __restrict__ partialCount,
    float* __restrict__ aux_out, int* __restrict__ descs)
{
    __shared__ float sL[256];
    __shared__ int   sC[256];
    int tid = threadIdx.x;
    int e = tid & 15, part = tid >> 4;
    float s = 0.f; int c = 0;
    #pragma unroll 8
    for (int b = 0; b < 32; ++b) {
        int blk = part * 32 + b;
        s += partialLoad[blk * NUM_EXPERTS + e];
        c += partialCount[blk * NUM_EXPERTS + e];
    }
    sL[tid] = s; sC[tid] = c;
    __syncthreads();
    if (tid < NUM_EXPERTS) {
        float sum = 0.f; int cc = 0;
        #pragma unroll
        for (int p = 0; p < 16; ++p) { sum += sL[p * 16 + tid]; cc += sC[p * 16 + tid]; }
        sL[tid] = sum; sC[tid] = cc;
    }
    __syncthreads();
    if (tid == 0) {
        int off = 0, n = 0;
        for (int e2 = 0; e2 < NUM_EXPERTS; ++e2) {
            offsets[e2] = off; cursor[e2] = off;
            int ne = sC[e2];
            int ntm = (ne + 255) >> 8;
            for (int tm = 0; tm < ntm; ++tm) descs[1 + n++] = (e2 << 8) | tm;
            off += ne;
        }
        offsets[NUM_EXPERTS] = off;
        descs[0] = n;
        float mean = 0.f;
        for (int e2 = 0; e2 < NUM_EXPERTS; ++e2) mean += sL[e2];
        mean *= (1.f / NUM_EXPERTS);
        float var = 0.f;
        for (int e2 = 0; e2 < NUM_EXPERTS; ++e2) {
            float d = sL[e2] - mean; var += d * d;
        }
        var *= (1.f / (NUM_EXPERTS - 1));       // ddof=1
        aux_out[0] = sqrtf(var) / mean;
    }
}

// ---- kernel 3: counting-sort scatter --------------------------------------
__global__ __launch_bounds__(256) void scatter_kernel(
    const int* __restrict__ eidx, int* __restrict__ cursor,
    int* __restrict__ perm)
{
    __shared__ int lc[NUM_EXPERTS];
    __shared__ int lbase[NUM_EXPERTS];
    int tid = threadIdx.x;
    if (tid < NUM_EXPERTS) lc[tid] = 0;
    __syncthreads();
    int t = blockIdx.x * 256 + tid;
    int e0 = eidx[2 * t], e1 = eidx[2 * t + 1];
    int lp0 = atomicAdd(&lc[e0], 1);
    int lp1 = atomicAdd(&lc[e1], 1);
    __syncthreads();
    if (tid < NUM_EXPERTS) lbase[tid] = atomicAdd(&cursor[tid], lc[tid]);
    __syncthreads();
    perm[lbase[e0] + lp0] = 2 * t;
    perm[lbase[e1] + lp1] = 2 * t + 1;
}

// ---- kernel 4: bf16 grouped GEMM, 256x256 tile, 8 waves, counted vmcnt -----
// grid 80*4; block -> (desc d = bid>>2, tn = bid&3). BK=64, dbuf 128 KB LDS.
// Same proven pipeline: stage t+1 -> vmcnt(8) -> barrier -> MFMA(t) ->
// lgkmcnt(0) -> barrier. y2[entry][col] bf16 aliases d_out exactly.
__global__ __launch_bounds__(512, 1) void expert_gemm_bf16(
    const unsigned short* __restrict__ xb, const unsigned short* __restrict__ Web,
    const int* __restrict__ perm, const int* __restrict__ offsets,
    const int* __restrict__ descs, unsigned short* __restrict__ y2)
{
    int d  = blockIdx.x >> 2;
    int tn = blockIdx.x & 3;
    if (d >= descs[0]) return;
    int de = descs[1 + d];
    int e = de >> 8, tm = de & 255;
    int g0 = offsets[e], g1 = offsets[e + 1];

    __shared__ unsigned short As[2][256 * 64];   // 2 x 32 KB
    __shared__ unsigned short Bs[2][256 * 64];   // 2 x 32 KB

    int tid = threadIdx.x, lane = tid & 63, w = tid >> 6;
    int wm = w >> 2, wn = w & 3;   // wave -> 128-row half x 64-col quarter

    // staging: chunk c = i*512 + tid; LDS slot (row=c>>3, ss=c&7);
    // pre-swizzled global source chunk s = ss ^ (row&7); reads undo the XOR.
    const char* aPtr[4];
    const char* bPtr[4];
    #pragma unroll
    for (int i = 0; i < 4; ++i) {
        int c = i * 512 + tid;
        int row = c >> 3, ss = c & 7;
        int s = ss ^ (row & 7);
        int gIdx = g0 + tm * 256 + row;
        if (gIdx > NSLOT - 1) gIdx = NSLOT - 1;         // clamp; masked at store
        int tok = perm[gIdx] >> 1;
        aPtr[i] = (const char*)(xb + (size_t)tok * IN_DIM + s * 8);
        bPtr[i] = (const char*)(Web + ((size_t)e * OUT_DIM + tn * 256 + row) * IN_DIM + s * 8);
    }

    f32x4 acc[8][4];
    #pragma unroll
    for (int m = 0; m < 8; ++m)
        #pragma unroll
        for (int n = 0; n < 4; ++n) {
            acc[m][n][0] = 0.f; acc[m][n][1] = 0.f;
            acc[m][n][2] = 0.f; acc[m][n][3] = 0.f;
        }

    // prologue: tile 0 -> buffer 0 (8 loads in flight)
    #pragma unroll
    for (int i = 0; i < 4; ++i)
        GLOAD_LDS16(aPtr[i], &As[0][(i * 512 + w * 64) * 8]);
    #pragma unroll
    for (int i = 0; i < 4; ++i)
        GLOAD_LDS16(bPtr[i], &Bs[0][(i * 512 + w * 64) * 8]);

    for (int t = 0; t < IN_DIM / 64; ++t) {
        int cur = t & 1;
        if (t < IN_DIM / 64 - 1) {
            int kByte = (t + 1) * 128;          // 64 cols * 2B per K-tile
            #pragma unroll
            for (int i = 0; i < 4; ++i)
                GLOAD_LDS16(aPtr[i] + kByte, &As[cur ^ 1][(i * 512 + w * 64) * 8]);
            #pragma unroll
            for (int i = 0; i < 4; ++i)
                GLOAD_LDS16(bPtr[i] + kByte, &Bs[cur ^ 1][(i * 512 + w * 64) * 8]);
            asm volatile("s_waitcnt vmcnt(8)" ::: "memory");
        } else {
            asm volatile("s_waitcnt vmcnt(0)" ::: "memory");
        }
        __builtin_amdgcn_sched_barrier(0);
        __builtin_amdgcn_s_barrier();          // tile t visible to all waves
        __builtin_amdgcn_sched_barrier(0);

        __builtin_amdgcn_s_setprio(1);
        #pragma unroll
        for (int ks = 0; ks < 2; ++ks) {
            bf16x8 aF[8], bF[4];
            #pragma unroll
            for (int m = 0; m < 8; ++m) {
                int row = wm * 128 + m * 16 + (lane & 15);
                int chunk = (ks * 4 + (lane >> 4)) ^ (row & 7);
                aF[m] = ldfrag(&As[cur][row * 64 + chunk * 8]);
            }
            #pragma unroll
            for (int n = 0; n < 4; ++n) {
                int row = wn * 64 + n * 16 + (lane & 15);
                int chunk = (ks * 4 + (lane >> 4)) ^ (row & 7);
                bF[n] = ldfrag(&Bs[cur][row * 64 + chunk * 8]);
            }
            #pragma unroll
            for (int m = 0; m < 8; ++m)
                #pragma unroll
                for (int n = 0; n < 4; ++n)
                    acc[m][n] = __builtin_amdgcn_mfma_f32_16x16x32_bf16(
                        aF[m], bF[n], acc[m][n], 0, 0, 0);
        }
        __builtin_amdgcn_s_setprio(0);

        asm volatile("s_waitcnt lgkmcnt(0)" ::: "memory");
        __builtin_amdgcn_sched_barrier(0);
        __builtin_amdgcn_s_barrier();
        __builtin_amdgcn_sched_barrier(0);
    }

    // epilogue: plain bf16 stores, y2[entry][col] = acc  (no atomics)
    #pragma unroll
    for (int m = 0; m < 8; ++m)
        #pragma unroll
        for (int r = 0; r < 4; ++r) {
            int row = wm * 128 + m * 16 + (lane >> 4) * 4 + r;
            int gIdx = g0 + tm * 256 + row;
            if (gIdx < g1) {
                int ent = perm[gIdx];
                size_t base = (size_t)ent * OUT_DIM + tn * 256 + wn * 64 + (lane & 15);
                #pragma unroll
                for (int n = 0; n < 4; ++n)
                    y2[base + n * 16] = f2bf(acc[m][n][r]);
            }
        }
}

// ---- kernel 5: in-place combine -------------------------------------------
// out row t (f32, 4 KB) aliases y2 rows 2t (first 2 KB) and 2t+1 (second 2 KB).
__global__ __launch_bounds__(256) void combine_kernel(
    float* __restrict__ out, const int* __restrict__ eidx,
    const float* __restrict__ prob, const float* __restrict__ be)
{
    int t   = blockIdx.x;
    int tid = threadIdx.x;
    int e0 = eidx[2 * t], e1 = eidx[2 * t + 1];
    float p0 = prob[2 * t], p1 = prob[2 * t + 1];

    const unsigned short* y = (const unsigned short*)out;
    u16x4 a = *(const u16x4*)(y + (size_t)(2 * t)     * OUT_DIM + tid * 4);
    u16x4 b = *(const u16x4*)(y + (size_t)(2 * t + 1) * OUT_DIM + tid * 4);
    float4 b0 = *(const float4*)(be + e0 * OUT_DIM + tid * 4);
    float4 b1 = *(const float4*)(be + e1 * OUT_DIM + tid * 4);

    float4 r;
    r.x = p0 * (bf2f(a[0]) + b0.x) + p1 * (bf2f(b[0]) + b1.x);
    r.y = p0 * (bf2f(a[1]) + b0.y) + p1 * (bf2f(b[1]) + b1.y);
    r.z = p0 * (bf2f(a[2]) + b0.z) + p1 * (bf2f(b[2]) + b1.z);
    r.w = p0 * (bf2f(a[3]) + b0.w) + p1 * (bf2f(b[3]) + b1.w);

    __syncthreads();   // all reads of this row complete before overwrite
    *(float4*)(out + (size_t)t * OUT_DIM + tid * 4) = r;
}

// ---- fallback: f32-input grouped GEMM with atomic epilogue (proven) --------
__global__ __launch_bounds__(256) void expert_gemm_f32(
    const float* __restrict__ x, const float* __restrict__ We,
    const float* __restrict__ be,
    const int* __restrict__ perm, const float* __restrict__ prob,
    const int* __restrict__ offsets, float* __restrict__ out)
{
    int e  = blockIdx.z;
    int g0 = offsets[e], g1 = offsets[e + 1];
    int ne = g1 - g0;
    int tm = blockIdx.y;
    if (tm * 128 >= ne) return;
    int tn = blockIdx.x;

    __shared__ unsigned short As[128 * 64];
    __shared__ unsigned short Bs[128 * 64];

    int tid  = threadIdx.x;
    int lane = tid & 63;
    int wave = tid >> 6;
    int wm = wave >> 1, wn = wave & 1;

    const float* aSrc[4]; bool aValid[4];
    #pragma unroll
    for (int i = 0; i < 4; ++i) {
        int c = tid + 256 * i;
        int row = c >> 3;
        int gIdx = g0 + tm * 128 + row;
        if (gIdx < g1) {
            int tok = perm[gIdx] >> 1;
            aSrc[i] = x + (size_t)tok * IN_DIM;
            aValid[i] = true;
        } else { aSrc[i] = x; aValid[i] = false; }
    }
    const float* bSrcBase = We + (size_t)e * OUT_DIM * IN_DIM;

    f32x4 acc[4][4];
    #pragma unroll
    for (int m = 0; m < 4; ++m)
        #pragma unroll
        for (int n = 0; n < 4; ++n) {
            acc[m][n][0] = 0.f; acc[m][n][1] = 0.f;
            acc[m][n][2] = 0.f; acc[m][n][3] = 0.f;
        }

    for (int k0 = 0; k0 < IN_DIM; k0 += 64) {
        __syncthreads();
        #pragma unroll
        for (int i = 0; i < 4; ++i) {
            int c = tid + 256 * i;
            int row = c >> 3, s = c & 7;
            float4 v0, v1;
            if (aValid[i]) {
                const float* p = aSrc[i] + k0 + s * 8;
                v0 = *(const float4*)p;
                v1 = *(const float4*)(p + 4);
            } else {
                v0 = make_float4(0.f, 0.f, 0.f, 0.f); v1 = v0;
            }
            int ss = s ^ (row & 7);
            *(short8*)&As[row * 64 + ss * 8] = pack8(v0, v1);
        }
        #pragma unroll
        for (int i = 0; i < 4; ++i) {
            int c = tid + 256 * i;
            int row = c >> 3, s = c & 7;
            int o = tn * 128 + row;
            const float* p = bSrcBase + (size_t)o * IN_DIM + k0 + s * 8;
            float4 v0 = *(const float4*)p;
            float4 v1 = *(const float4*)(p + 4);
            int ss = s ^ (row & 7);
            *(short8*)&Bs[row * 64 + ss * 8] = pack8(v0, v1);
        }
        __syncthreads();

        #pragma unroll
        for (int ks = 0; ks < 2; ++ks) {
            bf16x8 aF[4], bF[4];
            #pragma unroll
            for (int m = 0; m < 4; ++m) {
                int row = wm * 64 + m * 16 + (lane & 15);
                int chunk = (ks * 4 + (lane >> 4)) ^ (row & 7);
                aF[m] = ldfrag(&As[row * 64 + chunk * 8]);
            }
            #pragma unroll
            for (int n = 0; n < 4; ++n) {
                int row = wn * 64 + n * 16 + (lane & 15);
                int chunk = (ks * 4 + (lane >> 4)) ^ (row & 7);
                bF[n] = ldfrag(&Bs[row * 64 + chunk * 8]);
            }
            #pragma unroll
            for (int m = 0; m < 4; ++m)
                #pragma unroll
                for (int n = 0; n < 4; ++n)
                    acc[m][n] = __builtin_amdgcn_mfma_f32_16x16x32_bf16(
                        aF[m], bF[n], acc[m][n], 0, 0, 0);
        }
    }

    int   rowTok[4][4];
    float rowP[4][4];
    bool  rowV[4][4];
    #pragma unroll
    for (int m = 0; m < 4; ++m)
        #pragma unroll
        for (int r = 0; r < 4; ++r) {
            int row = wm * 64 + m * 16 + (lane >> 4) * 4 + r;
            int gIdx = g0 + tm * 128 + row;
            if (gIdx < g1) {
                int entry = perm[gIdx];
                rowTok[m][r] = entry >> 1;
                rowP[m][r]   = prob[entry];
                rowV[m][r]   = true;
            } else rowV[m][r] = false;
        }
    #pragma unroll
    for (int n = 0; n < 4; ++n) {
        int col = tn * 128 + wn * 64 + n * 16 + (lane & 15);
        float bias = be[e * OUT_DIM + col];
        #pragma unroll
        for (int m = 0; m < 4; ++m)
            #pragma unroll
            for (int r = 0; r < 4; ++r)
                if (rowV[m][r]) {
                    float v = acc[m][n][r] + bias;
                    atomicAdd(&out[(size_t)rowTok[m][r] * OUT_DIM + col],
                              rowP[m][r] * v);
                }
    }
}

// ---- launch ----------------------------------------------------------------
extern "C" void kernel_launch(void* const* d_in, const int* in_sizes, int n_in,
                              void* d_out, int out_size, void* d_ws, size_t ws_size,
                              hipStream_t stream) {
    const float* x  = (const float*)d_in[0];
    const float* Wg = (const float*)d_in[1];
    const float* bg = (const float*)d_in[2];
    const float* We = (const float*)d_in[3];
    const float* be = (const float*)d_in[4];
    float* out = (float*)d_out;

    const size_t WEB_BYTES = (size_t)NUM_EXPERTS * OUT_DIM * IN_DIM * 2;  // 32 MB
    const size_t XB_BYTES  = (size_t)BTOK * IN_DIM * 2;                   // 16 MB
    const size_t MISC      = (size_t)NSLOT * 12 + NGATE * NUM_EXPERTS * 8 + 8192;
    bool full = ws_size >= WEB_BYTES + XB_BYTES + MISC;

    char* w = (char*)d_ws;
    unsigned short* Web = nullptr;
    unsigned short* xb  = nullptr;
    if (full) {
        Web = (unsigned short*)w; w += WEB_BYTES;
        xb  = (unsigned short*)w; w += XB_BYTES;
    }
    int*   offsets     = (int*)w;    w += 128;
    int*   cursor      = (int*)w;    w += 64;
    int*   descs       = (int*)w;    w += (1 + MAX_DESC) * 4 + 60;
    int*   eidx        = (int*)w;    w += (size_t)NSLOT * 4;
    float* probArr     = (float*)w;  w += (size_t)NSLOT * 4;
    int*   perm        = (int*)w;    w += (size_t)NSLOT * 4;
    float* partialLoad = (float*)w;  w += NGATE * NUM_EXPERTS * 4;
    int*   partialCnt  = (int*)w;    w += NGATE * NUM_EXPERTS * 4;

    if (!full)
        hipMemsetAsync(d_out, 0, (size_t)out_size * sizeof(float), stream);

    prep_kernel<<<NGATE + NCONV, 256, 0, stream>>>(
        x, Wg, bg, eidx, probArr, partialLoad, partialCnt,
        full ? xb : nullptr, We, full ? Web : nullptr);
    finalize_gate<<<1, 256, 0, stream>>>(offsets, cursor, partialLoad, partialCnt,
                                         out + (size_t)BTOK * OUT_DIM, descs);
    scatter_kernel<<<BTOK / 256, 256, 0, stream>>>(eidx, cursor, perm);

    if (full) {
        expert_gemm_bf16<<<MAX_DESC * 4, 512, 0, stream>>>(
            xb, Web, perm, offsets, descs, (unsigned short*)d_out);
        combine_kernel<<<BTOK, 256, 0, stream>>>(out, eidx, probArr, be);
    } else {
        dim3 grid(OUT_DIM / 128, NSLOT / 128, NUM_EXPERTS);
        expert_gemm_f32<<<grid, 256, 0, stream>>>(x, We, be, perm, probArr,
                                                  offsets, out);
    }
}

// Round 11
// 127.286 us; speedup vs baseline: 1.2715x; 1.2715x over previous
//
#include <hip/hip_runtime.h>
#include <hip/hip_bf16.h>

#define NUM_EXPERTS 16
#define IN_DIM 1024
#define OUT_DIM 1024
#define BTOK 8192
#define NSLOT (2 * BTOK)
#define MCAP 320       // tile M capacity: ceil(1024-ish/320)=4 tiles/expert -> 64 descs
#define MAX_DESC 80
#define NGATE 512      // gate blocks: 256 threads, 16 tokens (4 per wave)

typedef __attribute__((ext_vector_type(4))) float f32x4;
typedef __attribute__((ext_vector_type(4))) int   i32x4;
typedef __attribute__((ext_vector_type(4))) unsigned short u16x4;
typedef __attribute__((ext_vector_type(8))) short short8;
typedef __attribute__((ext_vector_type(8))) __bf16 bf16x8;

// ---- helpers -------------------------------------------------------------

static __device__ inline unsigned short f2bf(float f) {
    union { float f; unsigned u; } v; v.f = f;
    unsigned u = v.u;
    unsigned r = (u + 0x7FFFu + ((u >> 16) & 1u)) >> 16;  // RNE
    return (unsigned short)r;
}

static __device__ inline float bf2f(unsigned short b) {
    union { unsigned u; float f; } v; v.u = ((unsigned)b) << 16;
    return v.f;
}

static __device__ inline short8 pack8(float4 a, float4 b) {
    short8 s;
    s[0] = (short)f2bf(a.x); s[1] = (short)f2bf(a.y);
    s[2] = (short)f2bf(a.z); s[3] = (short)f2bf(a.w);
    s[4] = (short)f2bf(b.x); s[5] = (short)f2bf(b.y);
    s[6] = (short)f2bf(b.z); s[7] = (short)f2bf(b.w);
    return s;
}

static __device__ inline bf16x8 ldfrag(const unsigned short* p) {
    i32x4 v = *(const i32x4*)p;                 // ds_read_b128
    return __builtin_bit_cast(bf16x8, v);
}

#define GLOAD_LDS16(g, l)                                                     \
    __builtin_amdgcn_global_load_lds(                                         \
        (const __attribute__((address_space(1))) void*)(g),                   \
        (__attribute__((address_space(3))) void*)(l), 16, 0, 0)

// ---- kernel 0: We f32 -> bf16 (standalone streaming; ~17 us proven) --------
__global__ __launch_bounds__(256) void convert_we(
    const float* __restrict__ We, unsigned short* __restrict__ Web)
{
    size_t i = ((size_t)blockIdx.x * 256 + threadIdx.x) * 8;
    const float4* s = (const float4*)(We + i);
    float4 v0 = s[0], v1 = s[1];
    *(short8*)(Web + i) = pack8(v0, v1);
}

// ---- kernel 1: gating + x->bf16 — LDS-FREE, register-grouped (R9 proven) ---
__global__ __launch_bounds__(256) void gate_kernel(
    const float* __restrict__ x, const float* __restrict__ Wg,
    const float* __restrict__ bg,
    int* __restrict__ eidx, float* __restrict__ prob,
    float* __restrict__ partialLoad, int* __restrict__ partialCount,
    unsigned short* __restrict__ xb)
{
    __shared__ float sLoad[NUM_EXPERTS];
    __shared__ int   sCnt[NUM_EXPERTS];

    int tid = threadIdx.x, lane = tid & 63, wave = tid >> 6;
    if (tid < NUM_EXPERTS) { sLoad[tid] = 0.f; sCnt[tid] = 0; }
    __syncthreads();

    const bool wb = (xb != nullptr);
    int tbase = blockIdx.x * 16 + wave * 4;

    const float4* xr0 = (const float4*)(x + (size_t)(tbase + 0) * IN_DIM);
    const float4* xr1 = (const float4*)(x + (size_t)(tbase + 1) * IN_DIM);
    const float4* xr2 = (const float4*)(x + (size_t)(tbase + 2) * IN_DIM);
    const float4* xr3 = (const float4*)(x + (size_t)(tbase + 3) * IN_DIM);

    float acc0[NUM_EXPERTS], acc1[NUM_EXPERTS], acc2[NUM_EXPERTS], acc3[NUM_EXPERTS];
    #pragma unroll
    for (int e = 0; e < NUM_EXPERTS; ++e) { acc0[e]=0.f; acc1[e]=0.f; acc2[e]=0.f; acc3[e]=0.f; }

    #pragma unroll
    for (int pass = 0; pass < 4; ++pass) {
        float4 xv0 = xr0[pass * 64 + lane];
        float4 xv1 = xr1[pass * 64 + lane];
        float4 xv2 = xr2[pass * 64 + lane];
        float4 xv3 = xr3[pass * 64 + lane];
        if (wb) {
            u16x4 b0, b1, b2, b3;
            b0[0]=f2bf(xv0.x); b0[1]=f2bf(xv0.y); b0[2]=f2bf(xv0.z); b0[3]=f2bf(xv0.w);
            b1[0]=f2bf(xv1.x); b1[1]=f2bf(xv1.y); b1[2]=f2bf(xv1.z); b1[3]=f2bf(xv1.w);
            b2[0]=f2bf(xv2.x); b2[1]=f2bf(xv2.y); b2[2]=f2bf(xv2.z); b2[3]=f2bf(xv2.w);
            b3[0]=f2bf(xv3.x); b3[1]=f2bf(xv3.y); b3[2]=f2bf(xv3.z); b3[3]=f2bf(xv3.w);
            size_t c = (size_t)(pass * 64 + lane) * 4;
            *(u16x4*)(xb + (size_t)(tbase + 0) * IN_DIM + c) = b0;
            *(u16x4*)(xb + (size_t)(tbase + 1) * IN_DIM + c) = b1;
            *(u16x4*)(xb + (size_t)(tbase + 2) * IN_DIM + c) = b2;
            *(u16x4*)(xb + (size_t)(tbase + 3) * IN_DIM + c) = b3;
        }
        int kb = pass * 256 + lane * 4;
        #pragma unroll
        for (int e = 0; e < NUM_EXPERTS; ++e) {
            float4 wv = *(const float4*)(Wg + e * IN_DIM + kb);
            acc0[e] += xv0.x*wv.x + xv0.y*wv.y + xv0.z*wv.z + xv0.w*wv.w;
            acc1[e] += xv1.x*wv.x + xv1.y*wv.y + xv1.z*wv.z + xv1.w*wv.w;
            acc2[e] += xv2.x*wv.x + xv2.y*wv.y + xv2.z*wv.z + xv2.w*wv.w;
            acc3[e] += xv3.x*wv.x + xv3.y*wv.y + xv3.z*wv.z + xv3.w*wv.w;
        }
    }

    #pragma unroll
    for (int e = 0; e < NUM_EXPERTS; ++e) {
        float v0 = acc0[e], v1 = acc1[e], v2 = acc2[e], v3 = acc3[e];
        #pragma unroll
        for (int off = 32; off; off >>= 1) {
            v0 += __shfl_xor(v0, off);
            v1 += __shfl_xor(v1, off);
            v2 += __shfl_xor(v2, off);
            v3 += __shfl_xor(v3, off);
        }
        acc0[e] = v0; acc1[e] = v1; acc2[e] = v2; acc3[e] = v3;
    }

    if (lane == 0) {
        #pragma unroll
        for (int j = 0; j < 4; ++j) {
            int t = tbase + j;
            float v0 = -1e30f, v1 = -1e30f; int i0 = 0, i1 = 0;
            #pragma unroll
            for (int e = 0; e < NUM_EXPERTS; ++e) {
                float a = (j == 0) ? acc0[e] : (j == 1) ? acc1[e]
                        : (j == 2) ? acc2[e] : acc3[e];
                float v = a + bg[e];
                if (v > v0) { v1 = v0; i1 = i0; v0 = v; i0 = e; }
                else if (v > v1) { v1 = v; i1 = e; }
            }
            float t1 = expf(v1 - v0);           // v1 <= v0
            float inv = 1.f / (1.f + t1);
            float p0 = inv, p1 = t1 * inv;
            eidx[2 * t]     = i0;  eidx[2 * t + 1] = i1;
            prob[2 * t]     = p0;  prob[2 * t + 1] = p1;
            atomicAdd(&sCnt[i0], 1);
            atomicAdd(&sCnt[i1], 1);
            atomicAdd(&sLoad[i0], p0);
            atomicAdd(&sLoad[i1], p1);
        }
    }
    __syncthreads();
    if (tid < NUM_EXPERTS) {
        partialLoad[blockIdx.x * NUM_EXPERTS + tid]  = sLoad[tid];
        partialCount[blockIdx.x * NUM_EXPERTS + tid] = sCnt[tid];
    }
}

// ---- kernel 2: offsets + aux loss + tile-descriptor list (MCAP-row tiles) --
__global__ __launch_bounds__(256) void finalize_gate(
    int* __restrict__ offsets, int* __restrict__ cursor,
    const float* __restrict__ partialLoad, const int* __restrict__ partialCount,
    float* __restrict__ aux_out, int* __restrict__ descs)
{
    __shared__ float sL[256];
    __shared__ int   sC[256];
    int tid = threadIdx.x;
    int e = tid & 15, part = tid >> 4;
    float s = 0.f; int c = 0;
    #pragma unroll 8
    for (int b = 0; b < 32; ++b) {
        int blk = part * 32 + b;
        s += partialLoad[blk * NUM_EXPERTS + e];
        c += partialCount[blk * NUM_EXPERTS + e];
    }
    sL[tid] = s; sC[tid] = c;
    __syncthreads();
    if (tid < NUM_EXPERTS) {
        float sum = 0.f; int cc = 0;
        #pragma unroll
        for (int p = 0; p < 16; ++p) { sum += sL[p * 16 + tid]; cc += sC[p * 16 + tid]; }
        sL[tid] = sum; sC[tid] = cc;
    }
    __syncthreads();
    if (tid == 0) {
        int off = 0, n = 0;
        for (int e2 = 0; e2 < NUM_EXPERTS; ++e2) {
            offsets[e2] = off; cursor[e2] = off;
            int ne = sC[e2];
            int ntm = (ne + MCAP - 1) / MCAP;
            for (int tm = 0; tm < ntm; ++tm) descs[1 + n++] = (e2 << 8) | tm;
            off += ne;
        }
        offsets[NUM_EXPERTS] = off;
        descs[0] = n;
        float mean = 0.f;
        for (int e2 = 0; e2 < NUM_EXPERTS; ++e2) mean += sL[e2];
        mean *= (1.f / NUM_EXPERTS);
        float var = 0.f;
        for (int e2 = 0; e2 < NUM_EXPERTS; ++e2) {
            float d = sL[e2] - mean; var += d * d;
        }
        var *= (1.f / (NUM_EXPERTS - 1));       // ddof=1
        aux_out[0] = sqrtf(var) / mean;
    }
}

// ---- kernel 3: counting-sort scatter --------------------------------------
__global__ __launch_bounds__(256) void scatter_kernel(
    const int* __restrict__ eidx, int* __restrict__ cursor,
    int* __restrict__ perm)
{
    __shared__ int lc[NUM_EXPERTS];
    __shared__ int lbase[NUM_EXPERTS];
    int tid = threadIdx.x;
    if (tid < NUM_EXPERTS) lc[tid] = 0;
    __syncthreads();
    int t = blockIdx.x * 256 + tid;
    int e0 = eidx[2 * t], e1 = eidx[2 * t + 1];
    int lp0 = atomicAdd(&lc[e0], 1);
    int lp1 = atomicAdd(&lc[e1], 1);
    __syncthreads();
    if (tid < NUM_EXPERTS) lbase[tid] = atomicAdd(&cursor[tid], lc[tid]);
    __syncthreads();
    perm[lbase[e0] + lp0] = 2 * t;
    perm[lbase[e1] + lp1] = 2 * t + 1;
}

// ---- kernel 4: bf16 grouped GEMM, 320x256 tile, balanced 1-block/CU grid ---
// grid 80*4; block -> (desc d = bid>>2, tn = bid&3). BK=64, dbuf 144 KB LDS.
// typ. descs=64 -> 256 active blocks = exactly 1/CU, zero tail.
// Proven counted-vmcnt pipeline: stage t+1 (9 loads) -> vmcnt(9) -> barrier
// -> MFMA(t) -> lgkmcnt(0) -> barrier. y2[entry][col] bf16 aliases d_out.
__global__ __launch_bounds__(512, 1) void expert_gemm_bf16(
    const unsigned short* __restrict__ xb, const unsigned short* __restrict__ Web,
    const int* __restrict__ perm, const int* __restrict__ offsets,
    const int* __restrict__ descs, unsigned short* __restrict__ y2)
{
    int d  = blockIdx.x >> 2;
    int tn = blockIdx.x & 3;
    if (d >= descs[0]) return;
    int de = descs[1 + d];
    int e = de >> 8, tm = de & 255;
    int g0 = offsets[e], g1 = offsets[e + 1];

    __shared__ unsigned short As[2][MCAP * 64];   // 2 x 40 KB
    __shared__ unsigned short Bs[2][256 * 64];    // 2 x 32 KB

    int tid = threadIdx.x, lane = tid & 63, w = tid >> 6;
    int wm = w >> 2, wn = w & 3;   // wave -> 160-row half x 64-col quarter

    // staging: chunk c = i*512 + tid; LDS slot (row=c>>3, ss=c&7);
    // pre-swizzled global source chunk s = ss ^ (row&7); reads undo the XOR.
    const char* aPtr[5];
    const char* bPtr[4];
    #pragma unroll
    for (int i = 0; i < 5; ++i) {
        int c = i * 512 + tid;
        int row = c >> 3, ss = c & 7;
        int s = ss ^ (row & 7);
        int gIdx = g0 + tm * MCAP + row;
        if (gIdx > NSLOT - 1) gIdx = NSLOT - 1;         // clamp; masked at store
        int tok = perm[gIdx] >> 1;
        aPtr[i] = (const char*)(xb + (size_t)tok * IN_DIM + s * 8);
    }
    #pragma unroll
    for (int i = 0; i < 4; ++i) {
        int c = i * 512 + tid;
        int row = c >> 3, ss = c & 7;
        int s = ss ^ (row & 7);
        bPtr[i] = (const char*)(Web + ((size_t)e * OUT_DIM + tn * 256 + row) * IN_DIM + s * 8);
    }

    f32x4 acc[10][4];
    #pragma unroll
    for (int m = 0; m < 10; ++m)
        #pragma unroll
        for (int n = 0; n < 4; ++n) {
            acc[m][n][0] = 0.f; acc[m][n][1] = 0.f;
            acc[m][n][2] = 0.f; acc[m][n][3] = 0.f;
        }

    // prologue: tile 0 -> buffer 0 (9 loads in flight)
    #pragma unroll
    for (int i = 0; i < 5; ++i)
        GLOAD_LDS16(aPtr[i], &As[0][(i * 512 + w * 64) * 8]);
    #pragma unroll
    for (int i = 0; i < 4; ++i)
        GLOAD_LDS16(bPtr[i], &Bs[0][(i * 512 + w * 64) * 8]);

    for (int t = 0; t < IN_DIM / 64; ++t) {
        int cur = t & 1;
        if (t < IN_DIM / 64 - 1) {
            int kByte = (t + 1) * 128;          // 64 cols * 2B per K-tile
            #pragma unroll
            for (int i = 0; i < 5; ++i)
                GLOAD_LDS16(aPtr[i] + kByte, &As[cur ^ 1][(i * 512 + w * 64) * 8]);
            #pragma unroll
            for (int i = 0; i < 4; ++i)
                GLOAD_LDS16(bPtr[i] + kByte, &Bs[cur ^ 1][(i * 512 + w * 64) * 8]);
            // wait for the 9 OLDEST (tile t); tile t+1 stays in flight
            asm volatile("s_waitcnt vmcnt(9)" ::: "memory");
        } else {
            asm volatile("s_waitcnt vmcnt(0)" ::: "memory");
        }
        __builtin_amdgcn_sched_barrier(0);
        __builtin_amdgcn_s_barrier();          // tile t visible to all waves
        __builtin_amdgcn_sched_barrier(0);

        __builtin_amdgcn_s_setprio(1);
        #pragma unroll
        for (int ks = 0; ks < 2; ++ks) {
            bf16x8 aF[10], bF[4];
            #pragma unroll
            for (int m = 0; m < 10; ++m) {
                int row = wm * 160 + m * 16 + (lane & 15);
                int chunk = (ks * 4 + (lane >> 4)) ^ (row & 7);
                aF[m] = ldfrag(&As[cur][row * 64 + chunk * 8]);
            }
            #pragma unroll
            for (int n = 0; n < 4; ++n) {
                int row = wn * 64 + n * 16 + (lane & 15);
                int chunk = (ks * 4 + (lane >> 4)) ^ (row & 7);
                bF[n] = ldfrag(&Bs[cur][row * 64 + chunk * 8]);
            }
            #pragma unroll
            for (int m = 0; m < 10; ++m)
                #pragma unroll
                for (int n = 0; n < 4; ++n)
                    acc[m][n] = __builtin_amdgcn_mfma_f32_16x16x32_bf16(
                        aF[m], bF[n], acc[m][n], 0, 0, 0);
        }
        __builtin_amdgcn_s_setprio(0);

        asm volatile("s_waitcnt lgkmcnt(0)" ::: "memory");
        __builtin_amdgcn_sched_barrier(0);
        __builtin_amdgcn_s_barrier();
        __builtin_amdgcn_sched_barrier(0);
    }

    // epilogue: plain bf16 stores, y2[entry][col] = acc  (no atomics)
    #pragma unroll
    for (int m = 0; m < 10; ++m)
        #pragma unroll
        for (int r = 0; r < 4; ++r) {
            int row = wm * 160 + m * 16 + (lane >> 4) * 4 + r;
            int gIdx = g0 + tm * MCAP + row;
            if (gIdx < g1) {
                int ent = perm[gIdx];
                size_t base = (size_t)ent * OUT_DIM + tn * 256 + wn * 64 + (lane & 15);
                #pragma unroll
                for (int n = 0; n < 4; ++n)
                    y2[base + n * 16] = f2bf(acc[m][n][r]);
            }
        }
}

// ---- kernel 5: in-place combine -------------------------------------------
// out row t (f32, 4 KB) aliases y2 rows 2t (first 2 KB) and 2t+1 (second 2 KB).
__global__ __launch_bounds__(256) void combine_kernel(
    float* __restrict__ out, const int* __restrict__ eidx,
    const float* __restrict__ prob, const float* __restrict__ be)
{
    int t   = blockIdx.x;
    int tid = threadIdx.x;
    int e0 = eidx[2 * t], e1 = eidx[2 * t + 1];
    float p0 = prob[2 * t], p1 = prob[2 * t + 1];

    const unsigned short* y = (const unsigned short*)out;
    u16x4 a = *(const u16x4*)(y + (size_t)(2 * t)     * OUT_DIM + tid * 4);
    u16x4 b = *(const u16x4*)(y + (size_t)(2 * t + 1) * OUT_DIM + tid * 4);
    float4 b0 = *(const float4*)(be + e0 * OUT_DIM + tid * 4);
    float4 b1 = *(const float4*)(be + e1 * OUT_DIM + tid * 4);

    float4 r;
    r.x = p0 * (bf2f(a[0]) + b0.x) + p1 * (bf2f(b[0]) + b1.x);
    r.y = p0 * (bf2f(a[1]) + b0.y) + p1 * (bf2f(b[1]) + b1.y);
    r.z = p0 * (bf2f(a[2]) + b0.z) + p1 * (bf2f(b[2]) + b1.z);
    r.w = p0 * (bf2f(a[3]) + b0.w) + p1 * (bf2f(b[3]) + b1.w);

    __syncthreads();   // all reads of this row complete before overwrite
    *(float4*)(out + (size_t)t * OUT_DIM + tid * 4) = r;
}

// ---- fallback: f32-input grouped GEMM with atomic epilogue (proven) --------
__global__ __launch_bounds__(256) void expert_gemm_f32(
    const float* __restrict__ x, const float* __restrict__ We,
    const float* __restrict__ be,
    const int* __restrict__ perm, const float* __restrict__ prob,
    const int* __restrict__ offsets, float* __restrict__ out)
{
    int e  = blockIdx.z;
    int g0 = offsets[e], g1 = offsets[e + 1];
    int ne = g1 - g0;
    int tm = blockIdx.y;
    if (tm * 128 >= ne) return;
    int tn = blockIdx.x;

    __shared__ unsigned short As[128 * 64];
    __shared__ unsigned short Bs[128 * 64];

    int tid  = threadIdx.x;
    int lane = tid & 63;
    int wave = tid >> 6;
    int wm = wave >> 1, wn = wave & 1;

    const float* aSrc[4]; bool aValid[4];
    #pragma unroll
    for (int i = 0; i < 4; ++i) {
        int c = tid + 256 * i;
        int row = c >> 3;
        int gIdx = g0 + tm * 128 + row;
        if (gIdx < g1) {
            int tok = perm[gIdx] >> 1;
            aSrc[i] = x + (size_t)tok * IN_DIM;
            aValid[i] = true;
        } else { aSrc[i] = x; aValid[i] = false; }
    }
    const float* bSrcBase = We + (size_t)e * OUT_DIM * IN_DIM;

    f32x4 acc[4][4];
    #pragma unroll
    for (int m = 0; m < 4; ++m)
        #pragma unroll
        for (int n = 0; n < 4; ++n) {
            acc[m][n][0] = 0.f; acc[m][n][1] = 0.f;
            acc[m][n][2] = 0.f; acc[m][n][3] = 0.f;
        }

    for (int k0 = 0; k0 < IN_DIM; k0 += 64) {
        __syncthreads();
        #pragma unroll
        for (int i = 0; i < 4; ++i) {
            int c = tid + 256 * i;
            int row = c >> 3, s = c & 7;
            float4 v0, v1;
            if (aValid[i]) {
                const float* p = aSrc[i] + k0 + s * 8;
                v0 = *(const float4*)p;
                v1 = *(const float4*)(p + 4);
            } else {
                v0 = make_float4(0.f, 0.f, 0.f, 0.f); v1 = v0;
            }
            int ss = s ^ (row & 7);
            *(short8*)&As[row * 64 + ss * 8] = pack8(v0, v1);
        }
        #pragma unroll
        for (int i = 0; i < 4; ++i) {
            int c = tid + 256 * i;
            int row = c >> 3, s = c & 7;
            int o = tn * 128 + row;
            const float* p = bSrcBase + (size_t)o * IN_DIM + k0 + s * 8;
            float4 v0 = *(const float4*)p;
            float4 v1 = *(const float4*)(p + 4);
            int ss = s ^ (row & 7);
            *(short8*)&Bs[row * 64 + ss * 8] = pack8(v0, v1);
        }
        __syncthreads();

        #pragma unroll
        for (int ks = 0; ks < 2; ++ks) {
            bf16x8 aF[4], bF[4];
            #pragma unroll
            for (int m = 0; m < 4; ++m) {
                int row = wm * 64 + m * 16 + (lane & 15);
                int chunk = (ks * 4 + (lane >> 4)) ^ (row & 7);
                aF[m] = ldfrag(&As[row * 64 + chunk * 8]);
            }
            #pragma unroll
            for (int n = 0; n < 4; ++n) {
                int row = wn * 64 + n * 16 + (lane & 15);
                int chunk = (ks * 4 + (lane >> 4)) ^ (row & 7);
                bF[n] = ldfrag(&Bs[row * 64 + chunk * 8]);
            }
            #pragma unroll
            for (int m = 0; m < 4; ++m)
                #pragma unroll
                for (int n = 0; n < 4; ++n)
                    acc[m][n] = __builtin_amdgcn_mfma_f32_16x16x32_bf16(
                        aF[m], bF[n], acc[m][n], 0, 0, 0);
        }
    }

    int   rowTok[4][4];
    float rowP[4][4];
    bool  rowV[4][4];
    #pragma unroll
    for (int m = 0; m < 4; ++m)
        #pragma unroll
        for (int r = 0; r < 4; ++r) {
            int row = wm * 64 + m * 16 + (lane >> 4) * 4 + r;
            int gIdx = g0 + tm * 128 + row;
            if (gIdx < g1) {
                int entry = perm[gIdx];
                rowTok[m][r] = entry >> 1;
                rowP[m][r]   = prob[entry];
                rowV[m][r]   = true;
            } else rowV[m][r] = false;
        }
    #pragma unroll
    for (int n = 0; n < 4; ++n) {
        int col = tn * 128 + wn * 64 + n * 16 + (lane & 15);
        float bias = be[e * OUT_DIM + col];
        #pragma unroll
        for (int m = 0; m < 4; ++m)
            #pragma unroll
            for (int r = 0; r < 4; ++r)
                if (rowV[m][r]) {
                    float v = acc[m][n][r] + bias;
                    atomicAdd(&out[(size_t)rowTok[m][r] * OUT_DIM + col],
                              rowP[m][r] * v);
                }
    }
}

// ---- launch ----------------------------------------------------------------
extern "C" void kernel_launch(void* const* d_in, const int* in_sizes, int n_in,
                              void* d_out, int out_size, void* d_ws, size_t ws_size,
                              hipStream_t stream) {
    const float* x  = (const float*)d_in[0];
    const float* Wg = (const float*)d_in[1];
    const float* bg = (const float*)d_in[2];
    const float* We = (const float*)d_in[3];
    const float* be = (const float*)d_in[4];
    float* out = (float*)d_out;

    const size_t WEB_BYTES = (size_t)NUM_EXPERTS * OUT_DIM * IN_DIM * 2;  // 32 MB
    const size_t XB_BYTES  = (size_t)BTOK * IN_DIM * 2;                   // 16 MB
    const size_t MISC      = (size_t)NSLOT * 12 + NGATE * NUM_EXPERTS * 8 + 8192;
    bool full = ws_size >= WEB_BYTES + XB_BYTES + MISC;

    char* w = (char*)d_ws;
    unsigned short* Web = nullptr;
    unsigned short* xb  = nullptr;
    if (full) {
        Web = (unsigned short*)w; w += WEB_BYTES;
        xb  = (unsigned short*)w; w += XB_BYTES;
    }
    int*   offsets     = (int*)w;    w += 128;
    int*   cursor      = (int*)w;    w += 64;
    int*   descs       = (int*)w;    w += (1 + MAX_DESC) * 4 + 60;
    int*   eidx        = (int*)w;    w += (size_t)NSLOT * 4;
    float* probArr     = (float*)w;  w += (size_t)NSLOT * 4;
    int*   perm        = (int*)w;    w += (size_t)NSLOT * 4;
    float* partialLoad = (float*)w;  w += NGATE * NUM_EXPERTS * 4;
    int*   partialCnt  = (int*)w;    w += NGATE * NUM_EXPERTS * 4;

    if (!full)
        hipMemsetAsync(d_out, 0, (size_t)out_size * sizeof(float), stream);

    if (full)
        convert_we<<<NUM_EXPERTS * OUT_DIM * IN_DIM / (256 * 8), 256, 0, stream>>>(We, Web);

    gate_kernel<<<NGATE, 256, 0, stream>>>(x, Wg, bg, eidx, probArr,
                                           partialLoad, partialCnt,
                                           full ? xb : nullptr);
    finalize_gate<<<1, 256, 0, stream>>>(offsets, cursor, partialLoad, partialCnt,
                                         out + (size_t)BTOK * OUT_DIM, descs);
    scatter_kernel<<<BTOK / 256, 256, 0, stream>>>(eidx, cursor, perm);

    if (full) {
        expert_gemm_bf16<<<MAX_DESC * 4, 512, 0, stream>>>(
            xb, Web, perm, offsets, descs, (unsigned short*)d_out);
        combine_kernel<<<BTOK, 256, 0, stream>>>(out, eidx, probArr, be);
    } else {
        dim3 grid(OUT_DIM / 128, NSLOT / 128, NUM_EXPERTS);
        expert_gemm_f32<<<grid, 256, 0, stream>>>(x, We, be, perm, probArr,
                                                  offsets, out);
    }
}

// Round 12
// 112.766 us; speedup vs baseline: 1.4352x; 1.1288x over previous
//
#include <hip/hip_runtime.h>
#include <hip/hip_bf16.h>

#define NUM_EXPERTS 16
#define IN_DIM 1024
#define OUT_DIM 1024
#define BTOK 8192
#define NSLOT (2 * BTOK)
#define MCAP 320       // tile M capacity: ceil(1024-ish/320)=4 tiles/expert -> 64 descs
#define MAX_DESC 80
#define NGATE 1024     // gate blocks: 256 threads, 8 tokens (2 per wave)

typedef __attribute__((ext_vector_type(4))) float f32x4;
typedef __attribute__((ext_vector_type(4))) int   i32x4;
typedef __attribute__((ext_vector_type(4))) unsigned short u16x4;
typedef __attribute__((ext_vector_type(8))) short short8;
typedef __attribute__((ext_vector_type(8))) __bf16 bf16x8;

// ---- helpers -------------------------------------------------------------

static __device__ inline unsigned short f2bf(float f) {
    union { float f; unsigned u; } v; v.f = f;
    unsigned u = v.u;
    unsigned r = (u + 0x7FFFu + ((u >> 16) & 1u)) >> 16;  // RNE
    return (unsigned short)r;
}

static __device__ inline float bf2f(unsigned short b) {
    union { unsigned u; float f; } v; v.u = ((unsigned)b) << 16;
    return v.f;
}

static __device__ inline short8 pack8(float4 a, float4 b) {
    short8 s;
    s[0] = (short)f2bf(a.x); s[1] = (short)f2bf(a.y);
    s[2] = (short)f2bf(a.z); s[3] = (short)f2bf(a.w);
    s[4] = (short)f2bf(b.x); s[5] = (short)f2bf(b.y);
    s[6] = (short)f2bf(b.z); s[7] = (short)f2bf(b.w);
    return s;
}

static __device__ inline bf16x8 ldfrag(const unsigned short* p) {
    i32x4 v = *(const i32x4*)p;                 // ds_read_b128
    return __builtin_bit_cast(bf16x8, v);
}

#define GLOAD_LDS16(g, l)                                                     \
    __builtin_amdgcn_global_load_lds(                                         \
        (const __attribute__((address_space(1))) void*)(g),                   \
        (__attribute__((address_space(3))) void*)(l), 16, 0, 0)

// ---- kernel 0: We f32 -> bf16 (standalone streaming; ~17 us, BW roofline) --
__global__ __launch_bounds__(256) void convert_we(
    const float* __restrict__ We, unsigned short* __restrict__ Web)
{
    size_t i = ((size_t)blockIdx.x * 256 + threadIdx.x) * 8;
    const float4* s = (const float4*)(We + i);
    float4 v0 = s[0], v1 = s[1];
    *(short8*)(Web + i) = pack8(v0, v1);
}

// ---- kernel 1: gating + x->bf16 — LDS-free, 2 tokens/wave, hoisted x -------
// 1024 blocks x 256 threads = 4096 waves (16/CU). All 8 x float4 loads issue
// first (x latency overlaps Wg stream + FMA); Wg L2-resident.
__global__ __launch_bounds__(256) void gate_kernel(
    const float* __restrict__ x, const float* __restrict__ Wg,
    const float* __restrict__ bg,
    int* __restrict__ eidx, float* __restrict__ prob,
    float* __restrict__ partialLoad, int* __restrict__ partialCount,
    unsigned short* __restrict__ xb)
{
    __shared__ float sLoad[NUM_EXPERTS];
    __shared__ int   sCnt[NUM_EXPERTS];

    int tid = threadIdx.x, lane = tid & 63, wave = tid >> 6;
    if (tid < NUM_EXPERTS) { sLoad[tid] = 0.f; sCnt[tid] = 0; }
    __syncthreads();

    const bool wb = (xb != nullptr);
    int tbase = blockIdx.x * 8 + wave * 2;

    const float4* xr0 = (const float4*)(x + (size_t)(tbase + 0) * IN_DIM);
    const float4* xr1 = (const float4*)(x + (size_t)(tbase + 1) * IN_DIM);

    // hoist ALL x loads (8 float4 = 32 VGPR) so their latency overlaps below
    float4 xv0[4], xv1[4];
    #pragma unroll
    for (int pass = 0; pass < 4; ++pass) {
        xv0[pass] = xr0[pass * 64 + lane];
        xv1[pass] = xr1[pass * 64 + lane];
    }
    if (wb) {
        #pragma unroll
        for (int pass = 0; pass < 4; ++pass) {
            u16x4 b0, b1;
            b0[0]=f2bf(xv0[pass].x); b0[1]=f2bf(xv0[pass].y);
            b0[2]=f2bf(xv0[pass].z); b0[3]=f2bf(xv0[pass].w);
            b1[0]=f2bf(xv1[pass].x); b1[1]=f2bf(xv1[pass].y);
            b1[2]=f2bf(xv1[pass].z); b1[3]=f2bf(xv1[pass].w);
            size_t c = (size_t)(pass * 64 + lane) * 4;
            *(u16x4*)(xb + (size_t)(tbase + 0) * IN_DIM + c) = b0;
            *(u16x4*)(xb + (size_t)(tbase + 1) * IN_DIM + c) = b1;
        }
    }

    float acc0[NUM_EXPERTS], acc1[NUM_EXPERTS];
    #pragma unroll
    for (int e = 0; e < NUM_EXPERTS; ++e) { acc0[e] = 0.f; acc1[e] = 0.f; }

    #pragma unroll
    for (int pass = 0; pass < 4; ++pass) {
        int kb = pass * 256 + lane * 4;
        #pragma unroll
        for (int e = 0; e < NUM_EXPERTS; ++e) {
            float4 wv = *(const float4*)(Wg + e * IN_DIM + kb);
            acc0[e] += xv0[pass].x*wv.x + xv0[pass].y*wv.y
                     + xv0[pass].z*wv.z + xv0[pass].w*wv.w;
            acc1[e] += xv1[pass].x*wv.x + xv1[pass].y*wv.y
                     + xv1[pass].z*wv.z + xv1[pass].w*wv.w;
        }
    }

    #pragma unroll
    for (int e = 0; e < NUM_EXPERTS; ++e) {
        float v0 = acc0[e], v1 = acc1[e];
        #pragma unroll
        for (int off = 32; off; off >>= 1) {
            v0 += __shfl_xor(v0, off);
            v1 += __shfl_xor(v1, off);
        }
        acc0[e] = v0; acc1[e] = v1;
    }

    if (lane == 0) {
        #pragma unroll
        for (int j = 0; j < 2; ++j) {
            int t = tbase + j;
            float v0 = -1e30f, v1 = -1e30f; int i0 = 0, i1 = 0;
            #pragma unroll
            for (int e = 0; e < NUM_EXPERTS; ++e) {
                float a = (j == 0) ? acc0[e] : acc1[e];
                float v = a + bg[e];
                if (v > v0) { v1 = v0; i1 = i0; v0 = v; i0 = e; }
                else if (v > v1) { v1 = v; i1 = e; }
            }
            float t1 = expf(v1 - v0);           // v1 <= v0
            float inv = 1.f / (1.f + t1);
            float p0 = inv, p1 = t1 * inv;
            eidx[2 * t]     = i0;  eidx[2 * t + 1] = i1;
            prob[2 * t]     = p0;  prob[2 * t + 1] = p1;
            atomicAdd(&sCnt[i0], 1);
            atomicAdd(&sCnt[i1], 1);
            atomicAdd(&sLoad[i0], p0);
            atomicAdd(&sLoad[i1], p1);
        }
    }
    __syncthreads();
    if (tid < NUM_EXPERTS) {
        partialLoad[blockIdx.x * NUM_EXPERTS + tid]  = sLoad[tid];
        partialCount[blockIdx.x * NUM_EXPERTS + tid] = sCnt[tid];
    }
}

// ---- kernel 2: offsets + aux loss + tile-descriptor list (MCAP-row tiles) --
// 1024 partial blocks; 256 threads: e = tid&15, part = tid>>4 covers 64
__global__ __launch_bounds__(256) void finalize_gate(
    int* __restrict__ offsets, int* __restrict__ cursor,
    const float* __restrict__ partialLoad, const int* __restrict__ partialCount,
    float* __restrict__ aux_out, int* __restrict__ descs)
{
    __shared__ float sL[256];
    __shared__ int   sC[256];
    int tid = threadIdx.x;
    int e = tid & 15, part = tid >> 4;
    float s = 0.f; int c = 0;
    #pragma unroll 8
    for (int b = 0; b < 64; ++b) {
        int blk = part * 64 + b;
        s += partialLoad[blk * NUM_EXPERTS + e];
        c += partialCount[blk * NUM_EXPERTS + e];
    }
    sL[tid] = s; sC[tid] = c;
    __syncthreads();
    if (tid < NUM_EXPERTS) {
        float sum = 0.f; int cc = 0;
        #pragma unroll
        for (int p = 0; p < 16; ++p) { sum += sL[p * 16 + tid]; cc += sC[p * 16 + tid]; }
        sL[tid] = sum; sC[tid] = cc;
    }
    __syncthreads();
    if (tid == 0) {
        int off = 0, n = 0;
        for (int e2 = 0; e2 < NUM_EXPERTS; ++e2) {
            offsets[e2] = off; cursor[e2] = off;
            int ne = sC[e2];
            int ntm = (ne + MCAP - 1) / MCAP;
            for (int tm = 0; tm < ntm; ++tm) descs[1 + n++] = (e2 << 8) | tm;
            off += ne;
        }
        offsets[NUM_EXPERTS] = off;
        descs[0] = n;
        float mean = 0.f;
        for (int e2 = 0; e2 < NUM_EXPERTS; ++e2) mean += sL[e2];
        mean *= (1.f / NUM_EXPERTS);
        float var = 0.f;
        for (int e2 = 0; e2 < NUM_EXPERTS; ++e2) {
            float d = sL[e2] - mean; var += d * d;
        }
        var *= (1.f / (NUM_EXPERTS - 1));       // ddof=1
        aux_out[0] = sqrtf(var) / mean;
    }
}

// ---- kernel 3: counting-sort scatter --------------------------------------
__global__ __launch_bounds__(256) void scatter_kernel(
    const int* __restrict__ eidx, int* __restrict__ cursor,
    int* __restrict__ perm)
{
    __shared__ int lc[NUM_EXPERTS];
    __shared__ int lbase[NUM_EXPERTS];
    int tid = threadIdx.x;
    if (tid < NUM_EXPERTS) lc[tid] = 0;
    __syncthreads();
    int t = blockIdx.x * 256 + tid;
    int e0 = eidx[2 * t], e1 = eidx[2 * t + 1];
    int lp0 = atomicAdd(&lc[e0], 1);
    int lp1 = atomicAdd(&lc[e1], 1);
    __syncthreads();
    if (tid < NUM_EXPERTS) lbase[tid] = atomicAdd(&cursor[tid], lc[tid]);
    __syncthreads();
    perm[lbase[e0] + lp0] = 2 * t;
    perm[lbase[e1] + lp1] = 2 * t + 1;
}

// ---- kernel 4: bf16 grouped GEMM, 320x256 tile, XCD-local desc mapping -----
// bid = (d%8) + 8*(4*(d/8) + tn)  (bijective for 320 blocks): a desc's 4
// tn-blocks share XCD bid%8 -> A-panel read once per L2. BK=64, 144 KB dbuf.
// Proven counted-vmcnt pipeline: stage t+1 (9 loads) -> vmcnt(9) -> barrier
// -> MFMA(t) -> lgkmcnt(0) -> barrier. y2[entry][col] bf16 aliases d_out.
__global__ __launch_bounds__(512, 1) void expert_gemm_bf16(
    const unsigned short* __restrict__ xb, const unsigned short* __restrict__ Web,
    const int* __restrict__ perm, const int* __restrict__ offsets,
    const int* __restrict__ descs, unsigned short* __restrict__ y2)
{
    int bid = blockIdx.x;
    int xcd = bid & 7, j = bid >> 3;
    int d  = xcd + 8 * (j >> 2);
    int tn = j & 3;
    if (d >= descs[0]) return;
    int de = descs[1 + d];
    int e = de >> 8, tm = de & 255;
    int g0 = offsets[e], g1 = offsets[e + 1];

    __shared__ unsigned short As[2][MCAP * 64];   // 2 x 40 KB
    __shared__ unsigned short Bs[2][256 * 64];    // 2 x 32 KB

    int tid = threadIdx.x, lane = tid & 63, w = tid >> 6;
    int wm = w >> 2, wn = w & 3;   // wave -> 160-row half x 64-col quarter

    // staging: chunk c = i*512 + tid; LDS slot (row=c>>3, ss=c&7);
    // pre-swizzled global source chunk s = ss ^ (row&7); reads undo the XOR.
    const char* aPtr[5];
    const char* bPtr[4];
    #pragma unroll
    for (int i = 0; i < 5; ++i) {
        int c = i * 512 + tid;
        int row = c >> 3, ss = c & 7;
        int s = ss ^ (row & 7);
        int gIdx = g0 + tm * MCAP + row;
        if (gIdx > NSLOT - 1) gIdx = NSLOT - 1;         // clamp; masked at store
        int tok = perm[gIdx] >> 1;
        aPtr[i] = (const char*)(xb + (size_t)tok * IN_DIM + s * 8);
    }
    #pragma unroll
    for (int i = 0; i < 4; ++i) {
        int c = i * 512 + tid;
        int row = c >> 3, ss = c & 7;
        int s = ss ^ (row & 7);
        bPtr[i] = (const char*)(Web + ((size_t)e * OUT_DIM + tn * 256 + row) * IN_DIM + s * 8);
    }

    f32x4 acc[10][4];
    #pragma unroll
    for (int m = 0; m < 10; ++m)
        #pragma unroll
        for (int n = 0; n < 4; ++n) {
            acc[m][n][0] = 0.f; acc[m][n][1] = 0.f;
            acc[m][n][2] = 0.f; acc[m][n][3] = 0.f;
        }

    // prologue: tile 0 -> buffer 0 (9 loads in flight)
    #pragma unroll
    for (int i = 0; i < 5; ++i)
        GLOAD_LDS16(aPtr[i], &As[0][(i * 512 + w * 64) * 8]);
    #pragma unroll
    for (int i = 0; i < 4; ++i)
        GLOAD_LDS16(bPtr[i], &Bs[0][(i * 512 + w * 64) * 8]);

    for (int t = 0; t < IN_DIM / 64; ++t) {
        int cur = t & 1;
        if (t < IN_DIM / 64 - 1) {
            int kByte = (t + 1) * 128;          // 64 cols * 2B per K-tile
            #pragma unroll
            for (int i = 0; i < 5; ++i)
                GLOAD_LDS16(aPtr[i] + kByte, &As[cur ^ 1][(i * 512 + w * 64) * 8]);
            #pragma unroll
            for (int i = 0; i < 4; ++i)
                GLOAD_LDS16(bPtr[i] + kByte, &Bs[cur ^ 1][(i * 512 + w * 64) * 8]);
            // wait for the 9 OLDEST (tile t); tile t+1 stays in flight
            asm volatile("s_waitcnt vmcnt(9)" ::: "memory");
        } else {
            asm volatile("s_waitcnt vmcnt(0)" ::: "memory");
        }
        __builtin_amdgcn_sched_barrier(0);
        __builtin_amdgcn_s_barrier();          // tile t visible to all waves
        __builtin_amdgcn_sched_barrier(0);

        __builtin_amdgcn_s_setprio(1);
        #pragma unroll
        for (int ks = 0; ks < 2; ++ks) {
            bf16x8 aF[10], bF[4];
            #pragma unroll
            for (int m = 0; m < 10; ++m) {
                int row = wm * 160 + m * 16 + (lane & 15);
                int chunk = (ks * 4 + (lane >> 4)) ^ (row & 7);
                aF[m] = ldfrag(&As[cur][row * 64 + chunk * 8]);
            }
            #pragma unroll
            for (int n = 0; n < 4; ++n) {
                int row = wn * 64 + n * 16 + (lane & 15);
                int chunk = (ks * 4 + (lane >> 4)) ^ (row & 7);
                bF[n] = ldfrag(&Bs[cur][row * 64 + chunk * 8]);
            }
            #pragma unroll
            for (int m = 0; m < 10; ++m)
                #pragma unroll
                for (int n = 0; n < 4; ++n)
                    acc[m][n] = __builtin_amdgcn_mfma_f32_16x16x32_bf16(
                        aF[m], bF[n], acc[m][n], 0, 0, 0);
        }
        __builtin_amdgcn_s_setprio(0);

        asm volatile("s_waitcnt lgkmcnt(0)" ::: "memory");
        __builtin_amdgcn_sched_barrier(0);
        __builtin_amdgcn_s_barrier();
        __builtin_amdgcn_sched_barrier(0);
    }

    // epilogue: plain bf16 stores, y2[entry][col] = acc  (no atomics)
    #pragma unroll
    for (int m = 0; m < 10; ++m)
        #pragma unroll
        for (int r = 0; r < 4; ++r) {
            int row = wm * 160 + m * 16 + (lane >> 4) * 4 + r;
            int gIdx = g0 + tm * MCAP + row;
            if (gIdx < g1) {
                int ent = perm[gIdx];
                size_t base = (size_t)ent * OUT_DIM + tn * 256 + wn * 64 + (lane & 15);
                #pragma unroll
                for (int n = 0; n < 4; ++n)
                    y2[base + n * 16] = f2bf(acc[m][n][r]);
            }
        }
}

// ---- kernel 5: in-place combine -------------------------------------------
// out row t (f32, 4 KB) aliases y2 rows 2t (first 2 KB) and 2t+1 (second 2 KB).
__global__ __launch_bounds__(256) void combine_kernel(
    float* __restrict__ out, const int* __restrict__ eidx,
    const float* __restrict__ prob, const float* __restrict__ be)
{
    int t   = blockIdx.x;
    int tid = threadIdx.x;
    int e0 = eidx[2 * t], e1 = eidx[2 * t + 1];
    float p0 = prob[2 * t], p1 = prob[2 * t + 1];

    const unsigned short* y = (const unsigned short*)out;
    u16x4 a = *(const u16x4*)(y + (size_t)(2 * t)     * OUT_DIM + tid * 4);
    u16x4 b = *(const u16x4*)(y + (size_t)(2 * t + 1) * OUT_DIM + tid * 4);
    float4 b0 = *(const float4*)(be + e0 * OUT_DIM + tid * 4);
    float4 b1 = *(const float4*)(be + e1 * OUT_DIM + tid * 4);

    float4 r;
    r.x = p0 * (bf2f(a[0]) + b0.x) + p1 * (bf2f(b[0]) + b1.x);
    r.y = p0 * (bf2f(a[1]) + b0.y) + p1 * (bf2f(b[1]) + b1.y);
    r.z = p0 * (bf2f(a[2]) + b0.z) + p1 * (bf2f(b[2]) + b1.z);
    r.w = p0 * (bf2f(a[3]) + b0.w) + p1 * (bf2f(b[3]) + b1.w);

    __syncthreads();   // all reads of this row complete before overwrite
    *(float4*)(out + (size_t)t * OUT_DIM + tid * 4) = r;
}

// ---- fallback: f32-input grouped GEMM with atomic epilogue (proven) --------
__global__ __launch_bounds__(256) void expert_gemm_f32(
    const float* __restrict__ x, const float* __restrict__ We,
    const float* __restrict__ be,
    const int* __restrict__ perm, const float* __restrict__ prob,
    const int* __restrict__ offsets, float* __restrict__ out)
{
    int e  = blockIdx.z;
    int g0 = offsets[e], g1 = offsets[e + 1];
    int ne = g1 - g0;
    int tm = blockIdx.y;
    if (tm * 128 >= ne) return;
    int tn = blockIdx.x;

    __shared__ unsigned short As[128 * 64];
    __shared__ unsigned short Bs[128 * 64];

    int tid  = threadIdx.x;
    int lane = tid & 63;
    int wave = tid >> 6;
    int wm = wave >> 1, wn = wave & 1;

    const float* aSrc[4]; bool aValid[4];
    #pragma unroll
    for (int i = 0; i < 4; ++i) {
        int c = tid + 256 * i;
        int row = c >> 3;
        int gIdx = g0 + tm * 128 + row;
        if (gIdx < g1) {
            int tok = perm[gIdx] >> 1;
            aSrc[i] = x + (size_t)tok * IN_DIM;
            aValid[i] = true;
        } else { aSrc[i] = x; aValid[i] = false; }
    }
    const float* bSrcBase = We + (size_t)e * OUT_DIM * IN_DIM;

    f32x4 acc[4][4];
    #pragma unroll
    for (int m = 0; m < 4; ++m)
        #pragma unroll
        for (int n = 0; n < 4; ++n) {
            acc[m][n][0] = 0.f; acc[m][n][1] = 0.f;
            acc[m][n][2] = 0.f; acc[m][n][3] = 0.f;
        }

    for (int k0 = 0; k0 < IN_DIM; k0 += 64) {
        __syncthreads();
        #pragma unroll
        for (int i = 0; i < 4; ++i) {
            int c = tid + 256 * i;
            int row = c >> 3, s = c & 7;
            float4 v0, v1;
            if (aValid[i]) {
                const float* p = aSrc[i] + k0 + s * 8;
                v0 = *(const float4*)p;
                v1 = *(const float4*)(p + 4);
            } else {
                v0 = make_float4(0.f, 0.f, 0.f, 0.f); v1 = v0;
            }
            int ss = s ^ (row & 7);
            *(short8*)&As[row * 64 + ss * 8] = pack8(v0, v1);
        }
        #pragma unroll
        for (int i = 0; i < 4; ++i) {
            int c = tid + 256 * i;
            int row = c >> 3, s = c & 7;
            int o = tn * 128 + row;
            const float* p = bSrcBase + (size_t)o * IN_DIM + k0 + s * 8;
            float4 v0 = *(const float4*)p;
            float4 v1 = *(const float4*)(p + 4);
            int ss = s ^ (row & 7);
            *(short8*)&Bs[row * 64 + ss * 8] = pack8(v0, v1);
        }
        __syncthreads();

        #pragma unroll
        for (int ks = 0; ks < 2; ++ks) {
            bf16x8 aF[4], bF[4];
            #pragma unroll
            for (int m = 0; m < 4; ++m) {
                int row = wm * 64 + m * 16 + (lane & 15);
                int chunk = (ks * 4 + (lane >> 4)) ^ (row & 7);
                aF[m] = ldfrag(&As[row * 64 + chunk * 8]);
            }
            #pragma unroll
            for (int n = 0; n < 4; ++n) {
                int row = wn * 64 + n * 16 + (lane & 15);
                int chunk = (ks * 4 + (lane >> 4)) ^ (row & 7);
                bF[n] = ldfrag(&Bs[row * 64 + chunk * 8]);
            }
            #pragma unroll
            for (int m = 0; m < 4; ++m)
                #pragma unroll
                for (int n = 0; n < 4; ++n)
                    acc[m][n] = __builtin_amdgcn_mfma_f32_16x16x32_bf16(
                        aF[m], bF[n], acc[m][n], 0, 0, 0);
        }
    }

    int   rowTok[4][4];
    float rowP[4][4];
    bool  rowV[4][4];
    #pragma unroll
    for (int m = 0; m < 4; ++m)
        #pragma unroll
        for (int r = 0; r < 4; ++r) {
            int row = wm * 64 + m * 16 + (lane >> 4) * 4 + r;
            int gIdx = g0 + tm * 128 + row;
            if (gIdx < g1) {
                int entry = perm[gIdx];
                rowTok[m][r] = entry >> 1;
                rowP[m][r]   = prob[entry];
                rowV[m][r]   = true;
            } else rowV[m][r] = false;
        }
    #pragma unroll
    for (int n = 0; n < 4; ++n) {
        int col = tn * 128 + wn * 64 + n * 16 + (lane & 15);
        float bias = be[e * OUT_DIM + col];
        #pragma unroll
        for (int m = 0; m < 4; ++m)
            #pragma unroll
            for (int r = 0; r < 4; ++r)
                if (rowV[m][r]) {
                    float v = acc[m][n][r] + bias;
                    atomicAdd(&out[(size_t)rowTok[m][r] * OUT_DIM + col],
                              rowP[m][r] * v);
                }
    }
}

// ---- launch ----------------------------------------------------------------
extern "C" void kernel_launch(void* const* d_in, const int* in_sizes, int n_in,
                              void* d_out, int out_size, void* d_ws, size_t ws_size,
                              hipStream_t stream) {
    const float* x  = (const float*)d_in[0];
    const float* Wg = (const float*)d_in[1];
    const float* bg = (const float*)d_in[2];
    const float* We = (const float*)d_in[3];
    const float* be = (const float*)d_in[4];
    float* out = (float*)d_out;

    const size_t WEB_BYTES = (size_t)NUM_EXPERTS * OUT_DIM * IN_DIM * 2;  // 32 MB
    const size_t XB_BYTES  = (size_t)BTOK * IN_DIM * 2;                   // 16 MB
    const size_t MISC      = (size_t)NSLOT * 12 + (size_t)NGATE * NUM_EXPERTS * 8 + 8192;
    bool full = ws_size >= WEB_BYTES + XB_BYTES + MISC;

    char* w = (char*)d_ws;
    unsigned short* Web = nullptr;
    unsigned short* xb  = nullptr;
    if (full) {
        Web = (unsigned short*)w; w += WEB_BYTES;
        xb  = (unsigned short*)w; w += XB_BYTES;
    }
    int*   offsets     = (int*)w;    w += 128;
    int*   cursor      = (int*)w;    w += 64;
    int*   descs       = (int*)w;    w += (1 + MAX_DESC) * 4 + 60;
    int*   eidx        = (int*)w;    w += (size_t)NSLOT * 4;
    float* probArr     = (float*)w;  w += (size_t)NSLOT * 4;
    int*   perm        = (int*)w;    w += (size_t)NSLOT * 4;
    float* partialLoad = (float*)w;  w += (size_t)NGATE * NUM_EXPERTS * 4;
    int*   partialCnt  = (int*)w;    w += (size_t)NGATE * NUM_EXPERTS * 4;

    if (!full)
        hipMemsetAsync(d_out, 0, (size_t)out_size * sizeof(float), stream);

    if (full)
        convert_we<<<NUM_EXPERTS * OUT_DIM * IN_DIM / (256 * 8), 256, 0, stream>>>(We, Web);

    gate_kernel<<<NGATE, 256, 0, stream>>>(x, Wg, bg, eidx, probArr,
                                           partialLoad, partialCnt,
                                           full ? xb : nullptr);
    finalize_gate<<<1, 256, 0, stream>>>(offsets, cursor, partialLoad, partialCnt,
                                         out + (size_t)BTOK * OUT_DIM, descs);
    scatter_kernel<<<BTOK / 256, 256, 0, stream>>>(eidx, cursor, perm);

    if (full) {
        expert_gemm_bf16<<<MAX_DESC * 4, 512, 0, stream>>>(
            xb, Web, perm, offsets, descs, (unsigned short*)d_out);
        combine_kernel<<<BTOK, 256, 0, stream>>>(out, eidx, probArr, be);
    } else {
        dim3 grid(OUT_DIM / 128, NSLOT / 128, NUM_EXPERTS);
        expert_gemm_f32<<<grid, 256, 0, stream>>>(x, We, be, perm, probArr,
                                                  offsets, out);
    }
}